// Round 1
// 379.943 us; speedup vs baseline: 1.0620x; 1.0620x over previous
//
#include <hip/hip_runtime.h>
#include <hip/hip_bf16.h>
#include <hip/hip_fp16.h>
#include <math.h>

// Problem constants
#define BB 2
#define TT 2048
#define DD 1024
#define HH 16
#define DK 64
#define KT 128            // keys per attention tile

typedef _Float16 f16x8 __attribute__((ext_vector_type(8)));
typedef __fp16 fp16x2 __attribute__((ext_vector_type(2)));
typedef __attribute__((ext_vector_type(4))) float f32x4;
typedef __attribute__((ext_vector_type(2))) float f32x2;

// async 16B global->LDS (lane i writes ldsbase + i*16)
static __device__ __forceinline__ void g2lds16(const void* g, void* l) {
    __builtin_amdgcn_global_load_lds(
        (const __attribute__((address_space(1))) unsigned int*)g,
        (__attribute__((address_space(3))) unsigned int*)l, 16, 0, 0);
}

// w = (1 - acos(clip(s,±0.999))/pi)^8 for a pair; rs accumulates pair sums.
// acos/pi via A&S 4.4.45 deg-3 (|err|<=5e-5 rad); reference's max(.,1e-6)
// is dead (clamp => t >= 0.0142). float2 ops lower to v_pk_* on gfx950.
// VALU-trimmed: magnitude-only clamp (abs folds into v_min modifier),
// packed 1-ax, and branch-free t = 0.5 + copysign(0.5 - uq, s)
// (s>=0: 1-uq; s<0: uq). Saves ~10 cyc/pair vs cmp/sub/cndmask form.
static __device__ __forceinline__ f32x2 w8pair(f32x2 s, f32x2& rs) {
    f32x2 ax;
    ax.x = fminf(fabsf(s.x), 0.999f);
    ax.y = fminf(fabsf(s.y), 0.999f);
    f32x2 p = ax * -0.0059617f + 0.0236380f;
    p = p * ax + (-0.0675180f);
    p = p * ax + 0.49997851f;
    f32x2 om = 1.0f - ax;
    f32x2 u;
    u.x = sqrtf(om.x);
    u.y = sqrtf(om.y);
    f32x2 uq = u * p;
    f32x2 e = 0.5f - uq;
    f32x2 t;
    t.x = 0.5f + copysignf(e.x, s.x);
    t.y = 0.5f + copysignf(e.y, s.y);
    f32x2 t2 = t * t;
    f32x2 t4 = t2 * t2;
    f32x2 t8 = t4 * t4;
    rs += t8;
    return t8;
}
// one-instruction f16 pair pack (RTZ; |err|<=2^-11 rel, fine for W)
static __device__ __forceinline__ int packh2(f32x2 v) {
    union { fp16x2 h; int i; } u;
    u.h = __builtin_amdgcn_cvt_pkrtz(v.x, v.y);
    return u.i;
}

// ---------------------------------------------------------------------------
// fp32 -> f16 convert (n multiple of 2048; 8 elems/thread)
// ---------------------------------------------------------------------------
__global__ __launch_bounds__(256) void cvt_kernel(
    const float* __restrict__ src, _Float16* __restrict__ dst)
{
    const int i = (blockIdx.x * 256 + threadIdx.x) * 8;
    float4 a = *(const float4*)(src + i);
    float4 b = *(const float4*)(src + i + 4);
    union { _Float16 h[8]; int4 v; } u;
    u.h[0] = (_Float16)a.x; u.h[1] = (_Float16)a.y;
    u.h[2] = (_Float16)a.z; u.h[3] = (_Float16)a.w;
    u.h[4] = (_Float16)b.x; u.h[5] = (_Float16)b.y;
    u.h[6] = (_Float16)b.z; u.h[7] = (_Float16)b.w;
    *(int4*)(dst + i) = u.v;
}

// 4 weights at once (blockIdx.y selects)
__global__ __launch_bounds__(256) void wcvt_kernel(
    const float* __restrict__ s0, const float* __restrict__ s1,
    const float* __restrict__ s2, const float* __restrict__ s3,
    _Float16* __restrict__ d0, _Float16* __restrict__ d1,
    _Float16* __restrict__ d2, _Float16* __restrict__ d3)
{
    const float* s; _Float16* d;
    switch (blockIdx.y) {
        case 0: s = s0; d = d0; break;
        case 1: s = s1; d = d1; break;
        case 2: s = s2; d = d2; break;
        default: s = s3; d = d3; break;
    }
    const int i = (blockIdx.x * 256 + threadIdx.x) * 8;
    float4 a = *(const float4*)(s + i);
    float4 b = *(const float4*)(s + i + 4);
    union { _Float16 h[8]; int4 v; } u;
    u.h[0] = (_Float16)a.x; u.h[1] = (_Float16)a.y;
    u.h[2] = (_Float16)a.z; u.h[3] = (_Float16)a.w;
    u.h[4] = (_Float16)b.x; u.h[5] = (_Float16)b.y;
    u.h[6] = (_Float16)b.z; u.h[7] = (_Float16)b.w;
    *(int4*)(d + i) = u.v;
}

// ---------------------------------------------------------------------------
// Pure-f16 async MFMA GEMM: C[M,N] = (Ah [+ Al]) [M,K] @ B[N,K]^T (+bias).
// Inputs pre-converted f16. 64x128 tile, BK=64, 4 waves (2x2).
// LDS chunk-major [kc][row][8] so global_load_lds lane->slot is contiguous
// and frag ds_read_b128 is ~2-way bank aliased (free).
// NPROD=1: projections (single product). NPROD=2: + Al·B (Wo GEMM).
// ---------------------------------------------------------------------------
template<int NPROD>
__global__ __launch_bounds__(256) void gemm_f16(
    const _Float16* __restrict__ Ah_g, const _Float16* __restrict__ Al_g,
    const _Float16* __restrict__ B_g, const float* __restrict__ bias,
    float* __restrict__ C, int M, int N, int K, int hasBias)
{
    __shared__ _Float16 Ahs[8][64][8];    //  8 KB
    __shared__ _Float16 Als[8][64][8];    //  8 KB (unused traffic if NPROD=1)
    __shared__ _Float16 Bhs[8][128][8];   // 16 KB

    const int t    = threadIdx.x;
    const int m0   = blockIdx.y * 64;
    const int n0   = blockIdx.x * 128;
    const int lane = t & 63;
    const int w    = t >> 6;
    const int wm   = w >> 1;
    const int wn   = w & 1;
    const int l15  = lane & 15;
    const int quad = lane >> 4;

    f32x4 acc[2][4];
#pragma unroll
    for (int i = 0; i < 2; ++i)
#pragma unroll
        for (int j = 0; j < 4; ++j) acc[i][j] = (f32x4)0.f;

    for (int k0 = 0; k0 < K; k0 += 64) {
        __syncthreads();   // previous chunk's frag reads done
        // staging: wave w handles kc = 2w, 2w+1
#pragma unroll
        for (int i = 0; i < 2; ++i) {
            const int cc = w * 2 + i;
            g2lds16(Ah_g + (size_t)(m0 + lane) * K + k0 + cc * 8, &Ahs[cc][0][0]);
            if (NPROD == 2)
                g2lds16(Al_g + (size_t)(m0 + lane) * K + k0 + cc * 8, &Als[cc][0][0]);
#pragma unroll
            for (int half = 0; half < 2; ++half)
                g2lds16(B_g + (size_t)(n0 + half * 64 + lane) * K + k0 + cc * 8,
                        &Bhs[cc][half * 64][0]);
        }
        __syncthreads();   // vmcnt drained

#pragma unroll
        for (int kh = 0; kh < 2; ++kh) {
            f16x8 ah[2], bh[4];
#pragma unroll
            for (int tm = 0; tm < 2; ++tm)
                ah[tm] = *(const f16x8*)&Ahs[kh * 4 + quad][wm * 32 + tm * 16 + l15][0];
#pragma unroll
            for (int tn = 0; tn < 4; ++tn)
                bh[tn] = *(const f16x8*)&Bhs[kh * 4 + quad][wn * 64 + tn * 16 + l15][0];
#pragma unroll
            for (int tm = 0; tm < 2; ++tm)
#pragma unroll
                for (int tn = 0; tn < 4; ++tn)
                    acc[tm][tn] = __builtin_amdgcn_mfma_f32_16x16x32_f16(
                        ah[tm], bh[tn], acc[tm][tn], 0, 0, 0);
            if (NPROD == 2) {
                f16x8 al[2];
#pragma unroll
                for (int tm = 0; tm < 2; ++tm)
                    al[tm] = *(const f16x8*)&Als[kh * 4 + quad][wm * 32 + tm * 16 + l15][0];
#pragma unroll
                for (int tm = 0; tm < 2; ++tm)
#pragma unroll
                    for (int tn = 0; tn < 4; ++tn)
                        acc[tm][tn] = __builtin_amdgcn_mfma_f32_16x16x32_f16(
                            al[tm], bh[tn], acc[tm][tn], 0, 0, 0);
            }
        }
    }

#pragma unroll
    for (int tm = 0; tm < 2; ++tm)
#pragma unroll
        for (int tn = 0; tn < 4; ++tn) {
            const int col  = n0 + wn * 64 + tn * 16 + l15;
            const float bv = hasBias ? bias[col] : 0.f;
            const int rowb = m0 + wm * 32 + tm * 16 + quad * 4;
#pragma unroll
            for (int r = 0; r < 4; ++r)
                C[(size_t)(rowb + r) * N + col] = acc[tm][tn][r] + bv;
        }
}

// ---------------------------------------------------------------------------
// Normalize each 64-wide head segment; emit f16 at [b][h][t][dk].
// ---------------------------------------------------------------------------
__global__ __launch_bounds__(256) void norm_kernel(
    const float* __restrict__ X, _Float16* __restrict__ H)
{
    const int seg  = blockIdx.x * 4 + (threadIdx.x >> 6);
    const int lane = threadIdx.x & 63;
    const int row  = seg >> 4;   // b*T + t
    const int h    = seg & 15;
    float v = X[(size_t)row * DD + h * DK + lane];
    float s = v * v;
    s += __shfl_xor(s, 1);
    s += __shfl_xor(s, 2);
    s += __shfl_xor(s, 4);
    s += __shfl_xor(s, 8);
    s += __shfl_xor(s, 16);
    s += __shfl_xor(s, 32);
    float n = sqrtf(s);
    float vn = v / fmaxf(n, 1e-12f);
    const int b  = row >> 11;
    const int tt = row & 2047;
    H[((size_t)(b * HH + h) * TT + tt) * DK + lane] = (_Float16)vn;
}

// ---------------------------------------------------------------------------
// V -> f16 transposed [b][h][d][T].
// ---------------------------------------------------------------------------
__global__ __launch_bounds__(256) void vtrans_kernel(
    const float* __restrict__ V0, _Float16* __restrict__ Vt)
{
    __shared__ _Float16 Vtmp[64][72];
    const int t  = threadIdx.x;
    const int t0 = blockIdx.x * 64;
    const int h  = blockIdx.y;
    const int b  = blockIdx.z;

    {
        const int i  = t >> 2;            // token row 0..63
        const int jc = (t & 3) * 16;      // dim chunk
        const float* src = V0 + (size_t)(b * TT + t0 + i) * DD + h * DK + jc;
#pragma unroll
        for (int c = 0; c < 4; ++c) {
            float4 v = *(const float4*)(src + c * 4);
            Vtmp[jc + c * 4 + 0][i] = (_Float16)v.x;
            Vtmp[jc + c * 4 + 1][i] = (_Float16)v.y;
            Vtmp[jc + c * 4 + 2][i] = (_Float16)v.z;
            Vtmp[jc + c * 4 + 3][i] = (_Float16)v.w;
        }
    }
    __syncthreads();
    {
        const int d  = t >> 2;
        const int kc = (t & 3) * 16;
        _Float16* dst = Vt + ((size_t)((b * HH + h) * DK + d)) * TT + t0 + kc;
        *(int4*)(dst)     = *(const int4*)&Vtmp[d][kc];
        *(int4*)(dst + 8) = *(const int4*)&Vtmp[d][kc + 8];
    }
}

// ---------------------------------------------------------------------------
// MFMA angular attention v6 — all-f16. Grid (T/64, H, B), 256 threads.
// Single-product f16 QK^T (sim err sigma ~2.5e-5, better than bf16 hi/lo).
// Phase A: wave w -> S^T for its 32 keys x 64 q; poly transform; f16 W via
// v_cvt_pkrtz. Phase B: wave w -> full O[16q x 64d] over 128 keys.
// Epilogue emits O split hi/lo f16 for the async Wo GEMM.
// v6: Q fragments live in registers (qf[4][2], loaded once from global) —
// drops Qhs from LDS: 60928 -> 51456 B => 3 blocks/CU (occupancy 21->31%).
// ---------------------------------------------------------------------------
__global__ __launch_bounds__(256) void attn_kernel(
    const _Float16* __restrict__ Qh_g, const _Float16* __restrict__ Kh_g,
    const _Float16* __restrict__ Vt_g,
    _Float16* __restrict__ Oh, _Float16* __restrict__ Ol)
{
    __shared__ _Float16 Khs[8][128][8];  // [dk-chunk][key][8]  16384 B
    __shared__ _Float16 Vts[16][64][8];  // [key-chunk][d][8]   16384 B
    __shared__ _Float16 Ws[64][136];     // [q][key]            17408 B
    __shared__ float Rbuf[4][64];        //                      1024 B
    __shared__ float Rfin[64];           //                       256 B

    const int t    = threadIdx.x;
    const int lane = t & 63;
    const int w    = t >> 6;
    const int l15  = lane & 15;
    const int quad = lane >> 4;
    const int q0   = blockIdx.x * 64;
    const int h    = blockIdx.y;
    const int b    = blockIdx.z;
    const size_t bh = (size_t)(b * HH + h);

    // Q fragments straight into registers (was LDS): frag (qt,s) for this
    // lane = Q[q0 + qt*16 + l15][s*32 + quad*8]. 8 x 16B loads, L2-served.
    f16x8 qf[4][2];
#pragma unroll
    for (int qt = 0; qt < 4; ++qt)
#pragma unroll
        for (int s = 0; s < 2; ++s)
            qf[qt][s] = *(const f16x8*)(Qh_g + (bh * TT + q0 + qt * 16 + l15) * DK
                                        + s * 32 + quad * 8);

    f32x4 acc[4];    // O[16q x 64d] for q-tile w
#pragma unroll
    for (int j = 0; j < 4; ++j) acc[j] = (f32x4)0.f;
    f32x2 rs2[4];
#pragma unroll
    for (int j = 0; j < 4; ++j) rs2[j] = (f32x2)0.f;

    const _Float16* kh_g = Kh_g + bh * TT * DK;
    const _Float16* vt_g = Vt_g + bh * (size_t)DK * TT;

    for (int k0 = 0; k0 < TT; k0 += KT) {
        __syncthreads();   // prev tile fully consumed

        // async staging: K 16 KB + V 16 KB, wave-partitioned
#pragma unroll
        for (int i = 0; i < 2; ++i) {
            const int cc = w * 2 + i;
#pragma unroll
            for (int half = 0; half < 2; ++half)
                g2lds16(kh_g + (size_t)(k0 + half * 64 + lane) * DK + cc * 8,
                        &Khs[cc][half * 64][0]);
        }
#pragma unroll
        for (int j = 0; j < 4; ++j) {
            const int kc = w * 4 + j;
            g2lds16(vt_g + (size_t)lane * TT + k0 + kc * 8, &Vts[kc][0][0]);
        }
        __syncthreads();   // vmcnt drained -> Khs/Vts valid

        // K frags for wave's 32 keys (hoisted across qt)
        f16x8 kf[2][2];    // [s][mt]
#pragma unroll
        for (int s = 0; s < 2; ++s)
#pragma unroll
            for (int mt = 0; mt < 2; ++mt)
                kf[s][mt] = *(const f16x8*)&Khs[s * 4 + quad][w * 32 + mt * 16 + l15][0];

        // Phase A: S^T for wave's 32 keys x 64 q, transform, write Ws
#pragma unroll
        for (int qt = 0; qt < 4; ++qt) {
            f32x4 c_[2];
            c_[0] = (f32x4)0.f;
            c_[1] = (f32x4)0.f;
#pragma unroll
            for (int s = 0; s < 2; ++s) {
#pragma unroll
                for (int mt = 0; mt < 2; ++mt)
                    c_[mt] = __builtin_amdgcn_mfma_f32_16x16x32_f16(
                        kf[s][mt], qf[qt][s], c_[mt], 0, 0, 0);
            }
#pragma unroll
            for (int mt = 0; mt < 2; ++mt) {
                f32x2 p01, p23;
                p01.x = c_[mt][0]; p01.y = c_[mt][1];
                p23.x = c_[mt][2]; p23.y = c_[mt][3];
                f32x2 w01 = w8pair(p01, rs2[qt]);
                f32x2 w23 = w8pair(p23, rs2[qt]);
                int2 pk;
                pk.x = packh2(w01);
                pk.y = packh2(w23);
                *(int2*)&Ws[qt * 16 + l15][w * 32 + mt * 16 + quad * 4] = pk;
            }
        }
        __syncthreads();   // Ws complete across waves

        // Phase B: PV for q-tile w over all 128 keys
#pragma unroll
        for (int kstep = 0; kstep < 4; ++kstep) {
            f16x8 av = *(const f16x8*)&Ws[16 * w + l15][kstep * 32 + quad * 8];
#pragma unroll
            for (int nd = 0; nd < 4; ++nd) {
                f16x8 bv = *(const f16x8*)&Vts[kstep * 4 + quad][nd * 16 + l15][0];
                acc[nd] = __builtin_amdgcn_mfma_f32_16x16x32_f16(
                    av, bv, acc[nd], 0, 0, 0);
            }
        }
    }

    // rowsum: rs2[qt] covers q = qt*16+l15 over wave's keys
#pragma unroll
    for (int qt = 0; qt < 4; ++qt) {
        float p = rs2[qt].x + rs2[qt].y;
        p += __shfl_xor(p, 16);
        p += __shfl_xor(p, 32);
        if (quad == 0) Rbuf[w][qt * 16 + l15] = p;
    }
    __syncthreads();
    if (t < 64) {
        float s = Rbuf[0][t] + Rbuf[1][t] + Rbuf[2][t] + Rbuf[3][t];
        Rfin[t] = 1.f / (s + 1e-6f);
    }
    __syncthreads();

    // store: O split hi/lo f16 (feeds the 2-product Wo GEMM)
#pragma unroll
    for (int r = 0; r < 4; ++r) {
        const int q = 16 * w + quad * 4 + r;
        const float inv = Rfin[q];
        const size_t base = (size_t)(b * TT + q0 + q) * DD + h * DK + l15;
#pragma unroll
        for (int nd = 0; nd < 4; ++nd) {
            float v = acc[nd][r] * inv;
            _Float16 hv = (_Float16)v;
            Oh[base + nd * 16] = hv;
            Ol[base + nd * 16] = (_Float16)(v - (float)hv);
        }
    }
}

// ---------------------------------------------------------------------------
extern "C" void kernel_launch(void* const* d_in, const int* in_sizes, int n_in,
                              void* d_out, int out_size, void* d_ws, size_t ws_size,
                              hipStream_t stream)
{
    const float* x  = (const float*)d_in[0];
    const float* Wq = (const float*)d_in[1];
    const float* Wk = (const float*)d_in[2];
    const float* Wv = (const float*)d_in[3];
    const float* Wo = (const float*)d_in[4];
    const float* bo = (const float*)d_in[5];
    float* out = (float*)d_out;

    const int M = BB * TT;   // 4096
    const int N = DD;
    const int K = DD;

    const size_t MB = 1024 * 1024;
    char* ws = (char*)d_ws;
    // [0,8):   xh f16                -> Kh f16 (after projections)
    // [8,16):  Wqh,Wkh,Wvh,Woh f16 (2 MB each; Woh persists)
    // [16,32): Q0 fp32               -> Oh [16,24) + Ol [24,32) (after norm Q)
    // [32,48): K0 fp32               -> Qh [32,40) + Vt [40,48) (after norm K)
    // [48,64): V0 fp32
    _Float16* xh  = (_Float16*)(ws);
    _Float16* Wqh = (_Float16*)(ws + 8 * MB);
    _Float16* Wkh = (_Float16*)(ws + 10 * MB);
    _Float16* Wvh = (_Float16*)(ws + 12 * MB);
    _Float16* Woh = (_Float16*)(ws + 14 * MB);
    float*    Q0  = (float*)(ws + 16 * MB);
    float*    K0  = (float*)(ws + 32 * MB);
    float*    V0  = (float*)(ws + 48 * MB);
    _Float16* Kh  = (_Float16*)(ws);
    _Float16* Qh  = (_Float16*)(ws + 32 * MB);
    _Float16* Vt  = (_Float16*)(ws + 40 * MB);
    _Float16* Oh  = (_Float16*)(ws + 16 * MB);
    _Float16* Ol  = (_Float16*)(ws + 24 * MB);

    dim3 gB(256);
    dim3 gGemm(N / 128, M / 64);   // (8, 64)

    // convert inputs to f16
    cvt_kernel<<<(M * DD) / 2048, gB, 0, stream>>>(x, xh);
    wcvt_kernel<<<dim3((DD * DD) / 2048, 4), gB, 0, stream>>>(
        Wq, Wk, Wv, Wo, Wqh, Wkh, Wvh, Woh);

    // projections (single-product f16)
    gemm_f16<1><<<gGemm, gB, 0, stream>>>(xh, nullptr, Wqh, nullptr, Q0, M, N, K, 0);
    gemm_f16<1><<<gGemm, gB, 0, stream>>>(xh, nullptr, Wkh, nullptr, K0, M, N, K, 0);
    gemm_f16<1><<<gGemm, gB, 0, stream>>>(xh, nullptr, Wvh, nullptr, V0, M, N, K, 0);

    // normalize + layout transforms (buffer reuse is stream-ordered)
    const int nSeg = M * HH;  // 65536
    norm_kernel<<<nSeg / 4, gB, 0, stream>>>(K0, Kh);   // K0 dead after
    norm_kernel<<<nSeg / 4, gB, 0, stream>>>(Q0, Qh);   // writes into old K0
    vtrans_kernel<<<dim3(TT / 64, HH, BB), gB, 0, stream>>>(V0, Vt);

    // fused angular attention -> O split f16 hi/lo (into old Q0 region)
    attn_kernel<<<dim3(TT / 64, HH, BB), gB, 0, stream>>>(Qh, Kh, Vt, Oh, Ol);

    // output projection: (Oh + Ol) @ Woh^T + bo
    gemm_f16<2><<<gGemm, gB, 0, stream>>>(Oh, Ol, Woh, bo, out, M, N, K, 1);
}